// Round 1
// baseline (2857.041 us; speedup 1.0000x reference)
//
#include <hip/hip_runtime.h>
#include <math.h>

#define BB 2
#define TT 2048
#define CC 768
#define HH 12
#define DD 64

// ---------------------------------------------------------------------------
// Generic 64x64-tile fp32 GEMM: A[M=4096, K=768] (row-major) @ W[768, N] + bias.
// mode 0: scatter-write into Q/K/V as [B,H,T,Dh]   (N = 2304)
// mode 1: plain write into O0 as [M, N]            (N = 768)
// 256 threads = 16x16, each computes a 4x4 micro-tile. BK=16.
// ---------------------------------------------------------------------------
__global__ __launch_bounds__(256) void gemm_tile(
    const float* __restrict__ A, const float* __restrict__ W,
    const float* __restrict__ bias, int N, int mode,
    float* __restrict__ O0, float* __restrict__ O1, float* __restrict__ O2) {
  const int Kdim = CC;
  __shared__ float As[16][65];  // [kk][m], +1 pad
  __shared__ float Bs[16][65];  // [kk][n], +1 pad
  const int bm = blockIdx.y * 64;
  const int bn = blockIdx.x * 64;
  const int tid = threadIdx.x;
  const int tx = tid & 15;
  const int ty = tid >> 4;

  float acc[4][4] = {};

  for (int k0 = 0; k0 < Kdim; k0 += 16) {
#pragma unroll
    for (int i = 0; i < 4; ++i) {
      int idx = tid + i * 256;          // 0..1023
      int m = idx >> 4, kk = idx & 15;
      As[kk][m] = A[(size_t)(bm + m) * Kdim + (k0 + kk)];
    }
#pragma unroll
    for (int i = 0; i < 4; ++i) {
      int idx = tid + i * 256;
      int kk = idx >> 6, n = idx & 63;
      Bs[kk][n] = W[(size_t)(k0 + kk) * N + (bn + n)];
    }
    __syncthreads();
#pragma unroll
    for (int kk = 0; kk < 16; ++kk) {
      float a[4], b[4];
#pragma unroll
      for (int i = 0; i < 4; ++i) a[i] = As[kk][ty * 4 + i];
#pragma unroll
      for (int j = 0; j < 4; ++j) b[j] = Bs[kk][tx * 4 + j];
#pragma unroll
      for (int i = 0; i < 4; ++i)
#pragma unroll
        for (int j = 0; j < 4; ++j) acc[i][j] += a[i] * b[j];
    }
    __syncthreads();
  }

#pragma unroll
  for (int i = 0; i < 4; ++i) {
    int row = bm + ty * 4 + i;          // 0..4095
    int b = row >> 11;                  // /2048
    int t = row & 2047;
#pragma unroll
    for (int j = 0; j < 4; ++j) {
      int col = bn + tx * 4 + j;
      float v = acc[i][j] + bias[col];
      if (mode == 0) {
        int which = col / CC;
        int c = col - which * CC;
        int h = c >> 6, d = c & 63;
        size_t di = ((size_t)((b * HH + h) * TT + t)) * DD + d;
        if (which == 0) O0[di] = v;
        else if (which == 1) O1[di] = v;
        else O2[di] = v;
      } else {
        O0[(size_t)row * N + col] = v;
      }
    }
  }
}

// ---------------------------------------------------------------------------
// Attention: one block (256 threads = 4 waves) per (b, h, q-row t).
// Scores for k<=t staged in LDS; block-wide max/sum via shfl + LDS; PV with
// d = lane (coalesced V reads), 4-way k-split reduced through LDS.
// Y written in [B, T, C] layout (c = h*64 + d) so proj GEMM reads row-major.
// ---------------------------------------------------------------------------
__global__ __launch_bounds__(256) void attn_kernel(
    const float* __restrict__ Q, const float* __restrict__ K,
    const float* __restrict__ V, float* __restrict__ Y) {
  const int t = blockIdx.x, h = blockIdx.y, b = blockIdx.z;
  const float* q  = Q + (((size_t)(b * HH + h)) * TT + t) * DD;
  const float* Kb = K + ((size_t)(b * HH + h)) * TT * DD;
  const float* Vb = V + ((size_t)(b * HH + h)) * TT * DD;

  __shared__ float qs[DD];
  __shared__ float sc[TT];
  __shared__ float red[4][DD];
  __shared__ float rbuf[8];

  const int tid = threadIdx.x;
  if (tid < DD) qs[tid] = q[tid];
  __syncthreads();

  const int nk = t + 1;  // causal: keys 0..t

  // --- scores + running max ---
  float mx = -1e30f;
  for (int k = tid; k < nk; k += 256) {
    const float* kr = Kb + (size_t)k * DD;
    float s = 0.f;
#pragma unroll
    for (int d = 0; d < DD; ++d) s += qs[d] * kr[d];
    s *= 0.125f;  // 1/sqrt(64)
    sc[k] = s;
    mx = fmaxf(mx, s);
  }
#pragma unroll
  for (int o = 32; o > 0; o >>= 1) mx = fmaxf(mx, __shfl_down(mx, o));
  if ((tid & 63) == 0) rbuf[tid >> 6] = mx;
  __syncthreads();
  if (tid == 0)
    rbuf[4] = fmaxf(fmaxf(rbuf[0], rbuf[1]), fmaxf(rbuf[2], rbuf[3]));
  __syncthreads();
  mx = rbuf[4];

  // --- exp + sum ---
  float sum = 0.f;
  for (int k = tid; k < nk; k += 256) {
    float e = __expf(sc[k] - mx);
    sc[k] = e;
    sum += e;
  }
#pragma unroll
  for (int o = 32; o > 0; o >>= 1) sum += __shfl_down(sum, o);
  if ((tid & 63) == 0) rbuf[tid >> 6] = sum;
  __syncthreads();
  if (tid == 0) rbuf[4] = (rbuf[0] + rbuf[1]) + (rbuf[2] + rbuf[3]);
  __syncthreads();
  const float inv = 1.0f / rbuf[4];

  // --- PV ---
  const int d = tid & 63, grp = tid >> 6;
  float acc = 0.f;
  for (int k = grp; k < nk; k += 4) acc += sc[k] * Vb[(size_t)k * DD + d];
  red[grp][d] = acc;
  __syncthreads();
  if (grp == 0) {
    float r = (red[0][d] + red[1][d]) + (red[2][d] + red[3][d]);
    Y[((size_t)(b * TT) + t) * CC + h * DD + d] = r * inv;
  }
}

extern "C" void kernel_launch(void* const* d_in, const int* in_sizes, int n_in,
                              void* d_out, int out_size, void* d_ws, size_t ws_size,
                              hipStream_t stream) {
  const float* x      = (const float*)d_in[0];
  const float* W_attn = (const float*)d_in[1];
  const float* b_attn = (const float*)d_in[2];
  const float* W_proj = (const float*)d_in[3];
  const float* b_proj = (const float*)d_in[4];
  float* out = (float*)d_out;

  const size_t per = (size_t)BB * HH * TT * DD;  // 3,145,728 floats
  float* Q = (float*)d_ws;
  float* K = Q + per;
  float* V = K + per;
  float* Y = V + per;   // [B,T,C] — total ws use: 4*per*4B = 50.3 MB

  // QKV: M=4096, N=2304  -> grid (2304/64, 4096/64)
  gemm_tile<<<dim3(36, 64), 256, 0, stream>>>(x, W_attn, b_attn, 3 * CC, 0, Q, K, V);
  // Attention: one block per (t, h, b)
  attn_kernel<<<dim3(TT, HH, BB), 256, 0, stream>>>(Q, K, V, Y);
  // Proj: M=4096, N=768 -> grid (768/64, 4096/64)
  gemm_tile<<<dim3(12, 64), 256, 0, stream>>>(Y, W_proj, b_proj, CC, 1, out, nullptr, nullptr);
}

// Round 2
// 560.377 us; speedup vs baseline: 5.0984x; 5.0984x over previous
//
#include <hip/hip_runtime.h>
#include <hip/hip_bf16.h>
#include <math.h>

#define BB 2
#define TT 2048
#define CC 768
#define HH 12
#define DD 64

typedef __attribute__((ext_vector_type(8))) short bf16x8;
typedef __attribute__((ext_vector_type(4))) float f32x4;

static __device__ __forceinline__ ushort f2bf(float f) {
  union { float f; unsigned u; } v; v.f = f;
  unsigned r = v.u + 0x7FFF + ((v.u >> 16) & 1);  // RNE
  return (ushort)(r >> 16);
}

// ---------------------------------------------------------------------------
// fp32 tiled GEMM (64x64 tile, 16x16 threads, 4x4 micro-tile), BK=16.
// mode 0: scatter-write bf16 into Q/K/V as [B,H,T,Dh]   (N = 2304)
// mode 1: fp32 write into Of as [M, N]                  (N = 768)
// ---------------------------------------------------------------------------
__global__ __launch_bounds__(256) void gemm_tile(
    const float* __restrict__ A, const float* __restrict__ W,
    const float* __restrict__ bias, int N, int mode,
    ushort* __restrict__ Qo, ushort* __restrict__ Ko, ushort* __restrict__ Vo,
    float* __restrict__ Of) {
  const int Kdim = CC;
  __shared__ float As[16][65];
  __shared__ float Bs[16][65];
  const int bm = blockIdx.y * 64;
  const int bn = blockIdx.x * 64;
  const int tid = threadIdx.x;
  const int tx = tid & 15;
  const int ty = tid >> 4;

  float acc[4][4] = {};

  for (int k0 = 0; k0 < Kdim; k0 += 16) {
#pragma unroll
    for (int i = 0; i < 4; ++i) {
      int idx = tid + i * 256;
      int m = idx >> 4, kk = idx & 15;
      As[kk][m] = A[(size_t)(bm + m) * Kdim + (k0 + kk)];
    }
#pragma unroll
    for (int i = 0; i < 4; ++i) {
      int idx = tid + i * 256;
      int kk = idx >> 6, n = idx & 63;
      Bs[kk][n] = W[(size_t)(k0 + kk) * N + (bn + n)];
    }
    __syncthreads();
#pragma unroll
    for (int kk = 0; kk < 16; ++kk) {
      float a[4], b[4];
#pragma unroll
      for (int i = 0; i < 4; ++i) a[i] = As[kk][ty * 4 + i];
#pragma unroll
      for (int j = 0; j < 4; ++j) b[j] = Bs[kk][tx * 4 + j];
#pragma unroll
      for (int i = 0; i < 4; ++i)
#pragma unroll
        for (int j = 0; j < 4; ++j) acc[i][j] += a[i] * b[j];
    }
    __syncthreads();
  }

#pragma unroll
  for (int i = 0; i < 4; ++i) {
    int row = bm + ty * 4 + i;
    int b = row >> 11;
    int t = row & 2047;
#pragma unroll
    for (int j = 0; j < 4; ++j) {
      int col = bn + tx * 4 + j;
      float v = acc[i][j] + bias[col];
      if (mode == 0) {
        int which = col / CC;
        int c = col - which * CC;
        int hh = c >> 6, d = c & 63;
        size_t di = ((size_t)((b * HH + hh) * TT + t)) * DD + d;
        ushort bv = f2bf(v);
        if (which == 0) Qo[di] = bv;
        else if (which == 1) Ko[di] = bv;
        else Vo[di] = bv;
      } else {
        Of[(size_t)row * N + col] = v;
      }
    }
  }
}

// ---------------------------------------------------------------------------
// Flash attention, bf16 MFMA 16x16x32.
// Block = 256 thr = 4 waves; Q-tile = 64 rows (16/wave); KV-tile = 32 keys.
// Per wave: QK^T -> 4 MFMA, online softmax (16-lane xor-shuffle row reduce),
// P -> per-wave LDS round trip -> PV 4 MFMA. Causality: wave-uniform tile
// guard (k0 <= q0w+15 ensures every row has >=1 valid key) + -1e30 mask.
// LDS rows padded (72 / 40 ushorts) so ds_read_b128 is a full permutation.
// ---------------------------------------------------------------------------
__global__ __launch_bounds__(256) void attn_mfma(
    const ushort* __restrict__ Q, const ushort* __restrict__ K,
    const ushort* __restrict__ V, float* __restrict__ Y) {
  const int qt = (int)gridDim.x - 1 - (int)blockIdx.x;  // heavy tiles first
  const int h = blockIdx.y, b = blockIdx.z;
  const size_t hb = ((size_t)(b * HH + h)) * TT * DD;

  __shared__ ushort Ks[32][72];     // [key][d], stride 144B (9*16B)
  __shared__ ushort Vt[64][40];     // [d][key], stride 80B  (5*16B)
  __shared__ ushort Ps[4][16][40];  // per-wave P, stride 80B

  const int tid = threadIdx.x;
  const int w = tid >> 6, lane = tid & 63;
  const int grp = lane >> 4, colk = lane & 15;
  const int q0w = qt * 64 + w * 16;

  // Q fragments: A-frag row = lane&15, k-elems 8*grp+j (+32 per d-half)
  bf16x8 qf[2];
  {
    const ushort* qp = Q + hb + (size_t)(q0w + colk) * DD + 8 * grp;
    qf[0] = *(const bf16x8*)(qp);
    qf[1] = *(const bf16x8*)(qp + 32);
  }

  f32x4 o[4] = {};
  float m[4], l[4];
#pragma unroll
  for (int r = 0; r < 4; ++r) { m[r] = -1e30f; l[r] = 0.f; }

  const int ntiles = 2 * qt + 2;
  const int skey = tid >> 3;        // staging: key 0..31
  const int sd = (tid & 7) * 8;     // staging: d base

  for (int it = 0; it < ntiles; ++it) {
    const int k0 = it * 32;
    // stage K tile [32][64] bf16 (16B per thread, coalesced)
    *(bf16x8*)&Ks[skey][sd] = *(const bf16x8*)(K + hb + (size_t)(k0 + skey) * DD + sd);
    // stage V transposed -> Vt[d][key]
    bf16x8 vv = *(const bf16x8*)(V + hb + (size_t)(k0 + skey) * DD + sd);
#pragma unroll
    for (int j = 0; j < 8; ++j) Vt[sd + j][skey] = (ushort)vv[j];
    __syncthreads();

    if (k0 <= q0w + 15) {           // wave-uniform causal guard
      f32x4 s0 = {}, s1 = {};
#pragma unroll
      for (int dh = 0; dh < 2; ++dh) {
        bf16x8 kf0 = *(const bf16x8*)&Ks[colk][8 * grp + 32 * dh];
        bf16x8 kf1 = *(const bf16x8*)&Ks[colk + 16][8 * grp + 32 * dh];
        s0 = __builtin_amdgcn_mfma_f32_16x16x32_bf16(qf[dh], kf0, s0, 0, 0, 0);
        s1 = __builtin_amdgcn_mfma_f32_16x16x32_bf16(qf[dh], kf1, s1, 0, 0, 0);
      }
#pragma unroll
      for (int r = 0; r < 4; ++r) {
        const int qg = q0w + grp * 4 + r;   // C/D: row=(lane>>4)*4+r
        float a0 = s0[r] * 0.125f, a1 = s1[r] * 0.125f;
        if (k0 + colk > qg) a0 = -1e30f;
        if (k0 + 16 + colk > qg) a1 = -1e30f;
        float pm = fmaxf(a0, a1);
#pragma unroll
        for (int off = 8; off; off >>= 1) pm = fmaxf(pm, __shfl_xor(pm, off));
        const float mn = fmaxf(m[r], pm);
        const float sc = __expf(m[r] - mn);
        m[r] = mn;
        float p0 = __expf(a0 - mn), p1 = __expf(a1 - mn);
        float ps = p0 + p1;
#pragma unroll
        for (int off = 8; off; off >>= 1) ps += __shfl_xor(ps, off);
        l[r] = l[r] * sc + ps;
#pragma unroll
        for (int n = 0; n < 4; ++n) o[n][r] *= sc;
        Ps[w][grp * 4 + r][colk] = f2bf(p0);
        Ps[w][grp * 4 + r][16 + colk] = f2bf(p1);
      }
      // PV: A = P (same-wave LDS round trip, lgkmcnt-ordered), B = Vt
      bf16x8 pf = *(const bf16x8*)&Ps[w][colk][8 * grp];
#pragma unroll
      for (int n = 0; n < 4; ++n) {
        bf16x8 vf = *(const bf16x8*)&Vt[colk + 16 * n][8 * grp];
        o[n] = __builtin_amdgcn_mfma_f32_16x16x32_bf16(pf, vf, o[n], 0, 0, 0);
      }
    }
    __syncthreads();
  }

  // epilogue: Y[b][t][h*64+d] fp32
#pragma unroll
  for (int r = 0; r < 4; ++r) {
    const int qg = q0w + grp * 4 + r;
    const float inv = 1.0f / l[r];
    float* yp = Y + ((size_t)(b * TT) + qg) * CC + h * DD;
#pragma unroll
    for (int n = 0; n < 4; ++n) yp[16 * n + colk] = o[n][r] * inv;
  }
}

extern "C" void kernel_launch(void* const* d_in, const int* in_sizes, int n_in,
                              void* d_out, int out_size, void* d_ws, size_t ws_size,
                              hipStream_t stream) {
  const float* x      = (const float*)d_in[0];
  const float* W_attn = (const float*)d_in[1];
  const float* b_attn = (const float*)d_in[2];
  const float* W_proj = (const float*)d_in[3];
  const float* b_proj = (const float*)d_in[4];
  float* out = (float*)d_out;

  const size_t perE = (size_t)BB * HH * TT * DD;  // 3,145,728
  ushort* Q = (ushort*)d_ws;
  ushort* K = Q + perE;
  ushort* V = K + perE;
  float*  Y = (float*)(V + perE);  // 18.9MB offset (4B aligned); +12.6MB fp32

  // QKV GEMM: M=4096, N=2304 -> bf16 Q/K/V in [B,H,T,Dh]
  gemm_tile<<<dim3(36, 64), 256, 0, stream>>>(x, W_attn, b_attn, 3 * CC, 0, Q, K, V, nullptr);
  // Flash attention: grid (T/64, H, B)
  attn_mfma<<<dim3(TT / 64, HH, BB), 256, 0, stream>>>(Q, K, V, Y);
  // Proj GEMM: M=4096, N=768 fp32
  gemm_tile<<<dim3(12, 64), 256, 0, stream>>>(Y, W_proj, b_proj, CC, 1, nullptr, nullptr, nullptr, out);
}

// Round 3
// 229.230 us; speedup vs baseline: 12.4636x; 2.4446x over previous
//
#include <hip/hip_runtime.h>
#include <hip/hip_bf16.h>
#include <math.h>

#define BB 2
#define TT 2048
#define CC 768
#define HH 12
#define DD 64
#define KD 768  // GEMM K dim (both GEMMs)

typedef __attribute__((ext_vector_type(8))) short bf16x8;
typedef __attribute__((ext_vector_type(4))) float f32x4;
typedef __attribute__((ext_vector_type(4))) float f32x4v;
typedef __attribute__((ext_vector_type(4))) ushort u16x4;

static __device__ __forceinline__ ushort f2bf(float f) {
  union { float f; unsigned u; } v; v.f = f;
  unsigned r = v.u + 0x7FFF + ((v.u >> 16) & 1);  // RNE
  return (ushort)(r >> 16);
}

// ---------------------------------------------------------------------------
// fp32 -> bf16 elementwise (n4 = n/4 float4 chunks)
// ---------------------------------------------------------------------------
__global__ __launch_bounds__(256) void cvt_bf16(const float* __restrict__ in,
                                                ushort* __restrict__ out, int n4) {
  int i = blockIdx.x * 256 + threadIdx.x;
  if (i >= n4) return;
  f32x4v v = ((const f32x4v*)in)[i];
  u16x4 o;
  o.x = f2bf(v.x); o.y = f2bf(v.y); o.z = f2bf(v.z); o.w = f2bf(v.w);
  ((u16x4*)out)[i] = o;
}

// ---------------------------------------------------------------------------
// W [K][N] fp32 -> Wt [N][K] bf16 (tiled transpose, both sides coalesced)
// ---------------------------------------------------------------------------
__global__ __launch_bounds__(256) void transpose_cvt(const float* __restrict__ W,
                                                     ushort* __restrict__ Wt,
                                                     int K, int N) {
  __shared__ float t[32][33];
  const int n0 = blockIdx.x * 32, k0 = blockIdx.y * 32;
  const int tx = threadIdx.x & 31, ty = threadIdx.x >> 5;  // 32 x 8
#pragma unroll
  for (int j = 0; j < 32; j += 8)
    t[ty + j][tx] = W[(size_t)(k0 + ty + j) * N + n0 + tx];
  __syncthreads();
#pragma unroll
  for (int j = 0; j < 32; j += 8)
    Wt[(size_t)(n0 + ty + j) * K + k0 + tx] = f2bf(t[tx][ty + j]);
}

// ---------------------------------------------------------------------------
// bf16 MFMA GEMM, m97 structure: 128x128 tile, BK=32, 4 waves, 4x4 frags/wave.
// A [M][768] bf16 k-contig; Bt [N][768] bf16 k-contig (pre-transposed).
// global_load_lds width=16 staging; XOR swizzle (elem ^ ((row&3)<<3)) applied
// on BOTH the pre-swizzled global source and the ds_read (rule #21).
// mode 0: scatter bf16 into Q/K/V [B,H,T,Dh] (N=2304)
// mode 1: fp32 write Of [M][N]               (N=768)
// ---------------------------------------------------------------------------
__global__ __launch_bounds__(256) void gemm_mfma(
    const ushort* __restrict__ A, const ushort* __restrict__ Bt,
    const float* __restrict__ bias, int N, int mode,
    ushort* __restrict__ Qo, ushort* __restrict__ Ko, ushort* __restrict__ Vo,
    float* __restrict__ Of) {
  __shared__ ushort As[128 * 32];
  __shared__ ushort Bs[128 * 32];
  const int tid = threadIdx.x;
  const int w = tid >> 6, lane = tid & 63;
  const int wr = w >> 1, wc = w & 1;
  const int grp = lane >> 4, colk = lane & 15;
  const int bm = blockIdx.y * 128, bn = blockIdx.x * 128;

  f32x4 acc[4][4] = {};

  auto* AsL = (__attribute__((address_space(3))) char*)As;
  auto* BsL = (__attribute__((address_space(3))) char*)Bs;

  for (int k0 = 0; k0 < KD; k0 += 32) {
#pragma unroll
    for (int i = 0; i < 2; ++i) {
      const int idx = tid + i * 256;           // 0..511
      const int row = idx >> 2, g = idx & 3;
      const int eoff = (g * 8) ^ ((row & 3) << 3);  // pre-swizzled source
      const ushort* sa = A + (size_t)(bm + row) * KD + k0 + eoff;
      const ushort* sb = Bt + (size_t)(bn + row) * KD + k0 + eoff;
      __builtin_amdgcn_global_load_lds(
          (const __attribute__((address_space(1))) void*)sa,
          (__attribute__((address_space(3))) void*)(AsL + w * 1024 + i * 4096), 16, 0, 0);
      __builtin_amdgcn_global_load_lds(
          (const __attribute__((address_space(1))) void*)sb,
          (__attribute__((address_space(3))) void*)(BsL + w * 1024 + i * 4096), 16, 0, 0);
    }
    __syncthreads();

    bf16x8 af[4], bf[4];
    const int sw = (colk & 3) << 3;
#pragma unroll
    for (int m = 0; m < 4; ++m)
      af[m] = *(const bf16x8*)&As[(wr * 64 + m * 16 + colk) * 32 + ((grp * 8) ^ sw)];
#pragma unroll
    for (int n = 0; n < 4; ++n)
      bf[n] = *(const bf16x8*)&Bs[(wc * 64 + n * 16 + colk) * 32 + ((grp * 8) ^ sw)];
#pragma unroll
    for (int m = 0; m < 4; ++m)
#pragma unroll
      for (int n = 0; n < 4; ++n)
        acc[m][n] = __builtin_amdgcn_mfma_f32_16x16x32_bf16(af[m], bf[n], acc[m][n], 0, 0, 0);
    __syncthreads();
  }

#pragma unroll
  for (int m = 0; m < 4; ++m) {
    const int gro = bm + wr * 64 + m * 16 + grp * 4;
#pragma unroll
    for (int n = 0; n < 4; ++n) {
      const int col = bn + wc * 64 + n * 16 + colk;
      const float bv = bias[col];
#pragma unroll
      for (int j = 0; j < 4; ++j) {
        const int row = gro + j;
        const float v = acc[m][n][j] + bv;
        if (mode == 0) {
          const int which = col / CC;
          const int c = col - which * CC;
          const int hh = c >> 6, d = c & 63;
          const int b = row >> 11, t = row & 2047;
          const size_t di = ((size_t)((b * HH + hh) * TT + t)) * DD + d;
          const ushort bvv = f2bf(v);
          if (which == 0) Qo[di] = bvv;
          else if (which == 1) Ko[di] = bvv;
          else Vo[di] = bvv;
        } else {
          Of[(size_t)row * N + col] = v;
        }
      }
    }
  }
}

// ---------------------------------------------------------------------------
// Flash attention, bf16 MFMA 16x16x32 (unchanged from round 2 except bf16 Y).
// ---------------------------------------------------------------------------
__global__ __launch_bounds__(256) void attn_mfma(
    const ushort* __restrict__ Q, const ushort* __restrict__ K,
    const ushort* __restrict__ V, ushort* __restrict__ Yb) {
  const int qt = (int)gridDim.x - 1 - (int)blockIdx.x;  // heavy tiles first
  const int h = blockIdx.y, b = blockIdx.z;
  const size_t hb = ((size_t)(b * HH + h)) * TT * DD;

  __shared__ ushort Ks[32][72];
  __shared__ ushort Vt[64][40];
  __shared__ ushort Ps[4][16][40];

  const int tid = threadIdx.x;
  const int w = tid >> 6, lane = tid & 63;
  const int grp = lane >> 4, colk = lane & 15;
  const int q0w = qt * 64 + w * 16;

  bf16x8 qf[2];
  {
    const ushort* qp = Q + hb + (size_t)(q0w + colk) * DD + 8 * grp;
    qf[0] = *(const bf16x8*)(qp);
    qf[1] = *(const bf16x8*)(qp + 32);
  }

  f32x4 o[4] = {};
  float m[4], l[4];
#pragma unroll
  for (int r = 0; r < 4; ++r) { m[r] = -1e30f; l[r] = 0.f; }

  const int ntiles = 2 * qt + 2;
  const int skey = tid >> 3;
  const int sd = (tid & 7) * 8;

  for (int it = 0; it < ntiles; ++it) {
    const int k0 = it * 32;
    *(bf16x8*)&Ks[skey][sd] = *(const bf16x8*)(K + hb + (size_t)(k0 + skey) * DD + sd);
    bf16x8 vv = *(const bf16x8*)(V + hb + (size_t)(k0 + skey) * DD + sd);
#pragma unroll
    for (int j = 0; j < 8; ++j) Vt[sd + j][skey] = (ushort)vv[j];
    __syncthreads();

    if (k0 <= q0w + 15) {
      f32x4 s0 = {}, s1 = {};
#pragma unroll
      for (int dh = 0; dh < 2; ++dh) {
        bf16x8 kf0 = *(const bf16x8*)&Ks[colk][8 * grp + 32 * dh];
        bf16x8 kf1 = *(const bf16x8*)&Ks[colk + 16][8 * grp + 32 * dh];
        s0 = __builtin_amdgcn_mfma_f32_16x16x32_bf16(qf[dh], kf0, s0, 0, 0, 0);
        s1 = __builtin_amdgcn_mfma_f32_16x16x32_bf16(qf[dh], kf1, s1, 0, 0, 0);
      }
#pragma unroll
      for (int r = 0; r < 4; ++r) {
        const int qg = q0w + grp * 4 + r;
        float a0 = s0[r] * 0.125f, a1 = s1[r] * 0.125f;
        if (k0 + colk > qg) a0 = -1e30f;
        if (k0 + 16 + colk > qg) a1 = -1e30f;
        float pm = fmaxf(a0, a1);
#pragma unroll
        for (int off = 8; off; off >>= 1) pm = fmaxf(pm, __shfl_xor(pm, off));
        const float mn = fmaxf(m[r], pm);
        const float sc = __expf(m[r] - mn);
        m[r] = mn;
        float p0 = __expf(a0 - mn), p1 = __expf(a1 - mn);
        float ps = p0 + p1;
#pragma unroll
        for (int off = 8; off; off >>= 1) ps += __shfl_xor(ps, off);
        l[r] = l[r] * sc + ps;
#pragma unroll
        for (int n = 0; n < 4; ++n) o[n][r] *= sc;
        Ps[w][grp * 4 + r][colk] = f2bf(p0);
        Ps[w][grp * 4 + r][16 + colk] = f2bf(p1);
      }
      bf16x8 pf = *(const bf16x8*)&Ps[w][colk][8 * grp];
#pragma unroll
      for (int n = 0; n < 4; ++n) {
        bf16x8 vf = *(const bf16x8*)&Vt[colk + 16 * n][8 * grp];
        o[n] = __builtin_amdgcn_mfma_f32_16x16x32_bf16(pf, vf, o[n], 0, 0, 0);
      }
    }
    __syncthreads();
  }

#pragma unroll
  for (int r = 0; r < 4; ++r) {
    const int qg = q0w + grp * 4 + r;
    const float inv = 1.0f / l[r];
    ushort* yp = Yb + ((size_t)(b * TT) + qg) * CC + h * DD;
#pragma unroll
    for (int n = 0; n < 4; ++n) yp[16 * n + colk] = f2bf(o[n][r] * inv);
  }
}

extern "C" void kernel_launch(void* const* d_in, const int* in_sizes, int n_in,
                              void* d_out, int out_size, void* d_ws, size_t ws_size,
                              hipStream_t stream) {
  const float* x      = (const float*)d_in[0];
  const float* W_attn = (const float*)d_in[1];
  const float* b_attn = (const float*)d_in[2];
  const float* W_proj = (const float*)d_in[3];
  const float* b_proj = (const float*)d_in[4];
  float* out = (float*)d_out;

  const size_t per = (size_t)BB * TT * CC;  // 3,145,728
  ushort* Q   = (ushort*)d_ws;
  ushort* K   = Q + per;
  ushort* V   = K + per;
  ushort* Yb  = V + per;
  ushort* xb  = Yb + per;
  ushort* Wat = xb + per;            // [2304][768]
  ushort* Wpt = Wat + (size_t)3 * CC * CC;  // [768][768]   total ~36.2 MB

  // conversions
  cvt_bf16<<<dim3((per / 4 + 255) / 256), 256, 0, stream>>>(x, xb, (int)(per / 4));
  transpose_cvt<<<dim3(3 * CC / 32, CC / 32), 256, 0, stream>>>(W_attn, Wat, CC, 3 * CC);
  transpose_cvt<<<dim3(CC / 32, CC / 32), 256, 0, stream>>>(W_proj, Wpt, CC, CC);

  // QKV: M=4096, N=2304 -> grid (18, 32)
  gemm_mfma<<<dim3(3 * CC / 128, BB * TT / 128), 256, 0, stream>>>(
      xb, Wat, b_attn, 3 * CC, 0, Q, K, V, nullptr);
  // attention: grid (32, 12, 2)
  attn_mfma<<<dim3(TT / 64, HH, BB), 256, 0, stream>>>(Q, K, V, Yb);
  // proj: M=4096, N=768 -> grid (6, 32)
  gemm_mfma<<<dim3(CC / 128, BB * TT / 128), 256, 0, stream>>>(
      Yb, Wpt, b_proj, CC, 1, nullptr, nullptr, nullptr, out);
}

// Round 4
// 160.623 us; speedup vs baseline: 17.7873x; 1.4271x over previous
//
#include <hip/hip_runtime.h>
#include <hip/hip_bf16.h>
#include <math.h>

#define BB 2
#define TT 2048
#define CC 768
#define HH 12
#define DD 64
#define KD 768  // GEMM K dim (both GEMMs)

typedef __attribute__((ext_vector_type(8))) short bf16x8;
typedef __attribute__((ext_vector_type(4))) float f32x4;
typedef __attribute__((ext_vector_type(4))) float f32x4v;
typedef __attribute__((ext_vector_type(4))) ushort u16x4;

static __device__ __forceinline__ ushort f2bf(float f) {
  union { float f; unsigned u; } v; v.f = f;
  unsigned r = v.u + 0x7FFF + ((v.u >> 16) & 1);  // RNE
  return (ushort)(r >> 16);
}

// ---------------------------------------------------------------------------
// fp32 -> bf16 elementwise (n4 = n/4 float4 chunks)
// ---------------------------------------------------------------------------
__global__ __launch_bounds__(256) void cvt_bf16(const float* __restrict__ in,
                                                ushort* __restrict__ out, int n4) {
  int i = blockIdx.x * 256 + threadIdx.x;
  if (i >= n4) return;
  f32x4v v = ((const f32x4v*)in)[i];
  u16x4 o;
  o.x = f2bf(v.x); o.y = f2bf(v.y); o.z = f2bf(v.z); o.w = f2bf(v.w);
  ((u16x4*)out)[i] = o;
}

// ---------------------------------------------------------------------------
// W [K][N] fp32 -> Wt [N][K] bf16 (tiled transpose, both sides coalesced)
// ---------------------------------------------------------------------------
__global__ __launch_bounds__(256) void transpose_cvt(const float* __restrict__ W,
                                                     ushort* __restrict__ Wt,
                                                     int K, int N) {
  __shared__ float t[32][33];
  const int n0 = blockIdx.x * 32, k0 = blockIdx.y * 32;
  const int tx = threadIdx.x & 31, ty = threadIdx.x >> 5;  // 32 x 8
#pragma unroll
  for (int j = 0; j < 32; j += 8)
    t[ty + j][tx] = W[(size_t)(k0 + ty + j) * N + n0 + tx];
  __syncthreads();
#pragma unroll
  for (int j = 0; j < 32; j += 8)
    Wt[(size_t)(n0 + ty + j) * K + k0 + tx] = f2bf(t[tx][ty + j]);
}

// ---------------------------------------------------------------------------
// V [bh][T][D] bf16 -> Vt [bh][D][T] bf16 (64x64 tiles via LDS)
// ---------------------------------------------------------------------------
__global__ __launch_bounds__(256) void vtrans(const ushort* __restrict__ V,
                                              ushort* __restrict__ Vt) {
  __shared__ ushort t[64][72];
  const int t0 = blockIdx.x * 64;
  const size_t base = (size_t)blockIdx.y * TT * DD;
  const int tid = threadIdx.x;
  const int r = tid >> 2, c = (tid & 3) * 16;
  *(bf16x8*)&t[r][c] = *(const bf16x8*)&V[base + (size_t)(t0 + r) * DD + c];
  *(bf16x8*)&t[r][c + 8] = *(const bf16x8*)&V[base + (size_t)(t0 + r) * DD + c + 8];
  __syncthreads();
  const int d = tid >> 2, tc = (tid & 3) * 16;
  bf16x8 o0, o1;
#pragma unroll
  for (int j = 0; j < 8; ++j) { o0[j] = (short)t[tc + j][d]; o1[j] = (short)t[tc + 8 + j][d]; }
  *(bf16x8*)&Vt[base + (size_t)d * TT + t0 + tc] = o0;
  *(bf16x8*)&Vt[base + (size_t)d * TT + t0 + tc + 8] = o1;
}

// ---------------------------------------------------------------------------
// bf16 MFMA GEMM (m97 structure) — unchanged from round 3 (verified).
// ---------------------------------------------------------------------------
__global__ __launch_bounds__(256) void gemm_mfma(
    const ushort* __restrict__ A, const ushort* __restrict__ Bt,
    const float* __restrict__ bias, int N, int mode,
    ushort* __restrict__ Qo, ushort* __restrict__ Ko, ushort* __restrict__ Vo,
    float* __restrict__ Of) {
  __shared__ ushort As[128 * 32];
  __shared__ ushort Bs[128 * 32];
  const int tid = threadIdx.x;
  const int w = tid >> 6, lane = tid & 63;
  const int wr = w >> 1, wc = w & 1;
  const int grp = lane >> 4, colk = lane & 15;
  const int bm = blockIdx.y * 128, bn = blockIdx.x * 128;

  f32x4 acc[4][4] = {};

  auto* AsL = (__attribute__((address_space(3))) char*)As;
  auto* BsL = (__attribute__((address_space(3))) char*)Bs;

  for (int k0 = 0; k0 < KD; k0 += 32) {
#pragma unroll
    for (int i = 0; i < 2; ++i) {
      const int idx = tid + i * 256;
      const int row = idx >> 2, g = idx & 3;
      const int eoff = (g * 8) ^ ((row & 3) << 3);
      const ushort* sa = A + (size_t)(bm + row) * KD + k0 + eoff;
      const ushort* sb = Bt + (size_t)(bn + row) * KD + k0 + eoff;
      __builtin_amdgcn_global_load_lds(
          (const __attribute__((address_space(1))) void*)sa,
          (__attribute__((address_space(3))) void*)(AsL + w * 1024 + i * 4096), 16, 0, 0);
      __builtin_amdgcn_global_load_lds(
          (const __attribute__((address_space(1))) void*)sb,
          (__attribute__((address_space(3))) void*)(BsL + w * 1024 + i * 4096), 16, 0, 0);
    }
    __syncthreads();

    bf16x8 af[4], bf[4];
    const int sw = (colk & 3) << 3;
#pragma unroll
    for (int m = 0; m < 4; ++m)
      af[m] = *(const bf16x8*)&As[(wr * 64 + m * 16 + colk) * 32 + ((grp * 8) ^ sw)];
#pragma unroll
    for (int n = 0; n < 4; ++n)
      bf[n] = *(const bf16x8*)&Bs[(wc * 64 + n * 16 + colk) * 32 + ((grp * 8) ^ sw)];
#pragma unroll
    for (int m = 0; m < 4; ++m)
#pragma unroll
      for (int n = 0; n < 4; ++n)
        acc[m][n] = __builtin_amdgcn_mfma_f32_16x16x32_bf16(af[m], bf[n], acc[m][n], 0, 0, 0);
    __syncthreads();
  }

#pragma unroll
  for (int m = 0; m < 4; ++m) {
    const int gro = bm + wr * 64 + m * 16 + grp * 4;
#pragma unroll
    for (int n = 0; n < 4; ++n) {
      const int col = bn + wc * 64 + n * 16 + colk;
      const float bv = bias[col];
#pragma unroll
      for (int j = 0; j < 4; ++j) {
        const int row = gro + j;
        const float v = acc[m][n][j] + bv;
        if (mode == 0) {
          const int which = col / CC;
          const int c = col - which * CC;
          const int hh = c >> 6, d = c & 63;
          const int b = row >> 11, t = row & 2047;
          const size_t di = ((size_t)((b * HH + hh) * TT + t)) * DD + d;
          const ushort bvv = f2bf(v);
          if (which == 0) Qo[di] = bvv;
          else if (which == 1) Ko[di] = bvv;
          else Vo[di] = bvv;
        } else {
          Of[(size_t)row * N + col] = v;
        }
      }
    }
  }
}

// ---------------------------------------------------------------------------
// Flash attention, bf16 MFMA 16x16x32. KVBLK=64, async-stage split (T14):
// next-tile K/V loaded global->reg before compute, written to LDS after the
// post-compute barrier. V pre-transposed in global ([bh][D][T]) so both K and
// Vt stage as b128 writes into stride-72 (conflict-free) LDS rows.
// ---------------------------------------------------------------------------
__global__ __launch_bounds__(256) void attn_mfma(
    const ushort* __restrict__ Q, const ushort* __restrict__ K,
    const ushort* __restrict__ Vt, ushort* __restrict__ Yb) {
  const int qt = (int)gridDim.x - 1 - (int)blockIdx.x;  // heavy tiles first
  const int h = blockIdx.y, b = blockIdx.z;
  const size_t hb = ((size_t)(b * HH + h)) * TT * DD;

  __shared__ ushort Ks[64][72];     // [key][d]
  __shared__ ushort Vs[64][72];     // [d][key]
  __shared__ ushort Ps[4][16][72];  // per-wave P [qrow][key]

  const int tid = threadIdx.x;
  const int w = tid >> 6, lane = tid & 63;
  const int grp = lane >> 4, colk = lane & 15;
  const int q0w = qt * 64 + w * 16;

  const ushort* Kg = K + hb;
  const ushort* Vg = Vt + hb;  // [d][t]

  // Q fragments
  bf16x8 qf[2];
  {
    const ushort* qp = Q + hb + (size_t)(q0w + colk) * DD + 8 * grp;
    qf[0] = *(const bf16x8*)(qp);
    qf[1] = *(const bf16x8*)(qp + 32);
  }

  f32x4 o[4] = {};
  float m[4], l[4];
#pragma unroll
  for (int r = 0; r < 4; ++r) { m[r] = -1e30f; l[r] = 0.f; }

  const int srow = tid >> 2;          // 0..63 (key-row for K, d-row for V)
  const int scol = (tid & 3) * 16;    // 0,16,32,48

  // prologue: stage tile 0
  {
    bf16x8 k0a = *(const bf16x8*)&Kg[(size_t)srow * DD + scol];
    bf16x8 k0b = *(const bf16x8*)&Kg[(size_t)srow * DD + scol + 8];
    bf16x8 v0a = *(const bf16x8*)&Vg[(size_t)srow * TT + scol];
    bf16x8 v0b = *(const bf16x8*)&Vg[(size_t)srow * TT + scol + 8];
    *(bf16x8*)&Ks[srow][scol] = k0a;
    *(bf16x8*)&Ks[srow][scol + 8] = k0b;
    *(bf16x8*)&Vs[srow][scol] = v0a;
    *(bf16x8*)&Vs[srow][scol + 8] = v0b;
  }
  __syncthreads();

  const int nt = qt + 1;
  for (int it = 0; it < nt; ++it) {
    const int k0 = it * 64;
    const bool pfn = (it + 1 < nt);
    bf16x8 nk0, nk1, nv0, nv1;
    if (pfn) {  // issue next-tile loads early; latency hides under compute
      nk0 = *(const bf16x8*)&Kg[(size_t)(k0 + 64 + srow) * DD + scol];
      nk1 = *(const bf16x8*)&Kg[(size_t)(k0 + 64 + srow) * DD + scol + 8];
      nv0 = *(const bf16x8*)&Vg[(size_t)srow * TT + k0 + 64 + scol];
      nv1 = *(const bf16x8*)&Vg[(size_t)srow * TT + k0 + 64 + scol + 8];
    }

    // ---- QK^T: 16q x 64k ----
    f32x4 s[4] = {};
#pragma unroll
    for (int dh = 0; dh < 2; ++dh) {
#pragma unroll
      for (int kb = 0; kb < 4; ++kb) {
        bf16x8 kf = *(const bf16x8*)&Ks[16 * kb + colk][8 * grp + 32 * dh];
        s[kb] = __builtin_amdgcn_mfma_f32_16x16x32_bf16(qf[dh], kf, s[kb], 0, 0, 0);
      }
    }

    // ---- online softmax (per q-row r) ----
#pragma unroll
    for (int r = 0; r < 4; ++r) {
      const int qg = q0w + grp * 4 + r;
      float a[4];
#pragma unroll
      for (int kb = 0; kb < 4; ++kb) {
        a[kb] = s[kb][r] * 0.125f;
        if (k0 + 16 * kb + colk > qg) a[kb] = -1e30f;
      }
      float pm = fmaxf(fmaxf(a[0], a[1]), fmaxf(a[2], a[3]));
#pragma unroll
      for (int off = 8; off; off >>= 1) pm = fmaxf(pm, __shfl_xor(pm, off));
      const float mn = fmaxf(m[r], pm);
      const float sc = __expf(m[r] - mn);
      m[r] = mn;
      float p[4], ps = 0.f;
#pragma unroll
      for (int kb = 0; kb < 4; ++kb) { p[kb] = __expf(a[kb] - mn); ps += p[kb]; }
#pragma unroll
      for (int off = 8; off; off >>= 1) ps += __shfl_xor(ps, off);
      l[r] = l[r] * sc + ps;
#pragma unroll
      for (int n = 0; n < 4; ++n) o[n][r] *= sc;
#pragma unroll
      for (int kb = 0; kb < 4; ++kb) Ps[w][grp * 4 + r][16 * kb + colk] = f2bf(p[kb]);
    }

    // ---- PV (same-wave LDS round trip, lgkmcnt-ordered) ----
    bf16x8 pf0 = *(const bf16x8*)&Ps[w][colk][8 * grp];
    bf16x8 pf1 = *(const bf16x8*)&Ps[w][colk][32 + 8 * grp];
#pragma unroll
    for (int n = 0; n < 4; ++n) {
      bf16x8 vf0 = *(const bf16x8*)&Vs[16 * n + colk][8 * grp];
      bf16x8 vf1 = *(const bf16x8*)&Vs[16 * n + colk][32 + 8 * grp];
      o[n] = __builtin_amdgcn_mfma_f32_16x16x32_bf16(pf0, vf0, o[n], 0, 0, 0);
      o[n] = __builtin_amdgcn_mfma_f32_16x16x32_bf16(pf1, vf1, o[n], 0, 0, 0);
    }

    if (pfn) {
      __syncthreads();  // all waves done reading tile it
      *(bf16x8*)&Ks[srow][scol] = nk0;
      *(bf16x8*)&Ks[srow][scol + 8] = nk1;
      *(bf16x8*)&Vs[srow][scol] = nv0;
      *(bf16x8*)&Vs[srow][scol + 8] = nv1;
      __syncthreads();  // tile it+1 visible
    }
  }

  // epilogue: Yb[b][t][h*64+d] bf16
#pragma unroll
  for (int r = 0; r < 4; ++r) {
    const int qg = q0w + grp * 4 + r;
    const float inv = 1.0f / l[r];
    ushort* yp = Yb + ((size_t)(b * TT) + qg) * CC + h * DD;
#pragma unroll
    for (int n = 0; n < 4; ++n) yp[16 * n + colk] = f2bf(o[n][r] * inv);
  }
}

extern "C" void kernel_launch(void* const* d_in, const int* in_sizes, int n_in,
                              void* d_out, int out_size, void* d_ws, size_t ws_size,
                              hipStream_t stream) {
  const float* x      = (const float*)d_in[0];
  const float* W_attn = (const float*)d_in[1];
  const float* b_attn = (const float*)d_in[2];
  const float* W_proj = (const float*)d_in[3];
  const float* b_proj = (const float*)d_in[4];
  float* out = (float*)d_out;

  const size_t per = (size_t)BB * TT * CC;  // 3,145,728
  ushort* Q   = (ushort*)d_ws;
  ushort* K   = Q + per;
  ushort* V   = K + per;
  ushort* Yb  = V + per;
  ushort* xb  = Yb + per;
  ushort* VtT = xb + per;                   // [bh][D][T]
  ushort* Wat = VtT + per;                  // [2304][768]
  ushort* Wpt = Wat + (size_t)3 * CC * CC;  // [768][768]  total ~42.5 MB

  // prep
  cvt_bf16<<<dim3((per / 4 + 255) / 256), 256, 0, stream>>>(x, xb, (int)(per / 4));
  transpose_cvt<<<dim3(3 * CC / 32, CC / 32), 256, 0, stream>>>(W_attn, Wat, CC, 3 * CC);
  transpose_cvt<<<dim3(CC / 32, CC / 32), 256, 0, stream>>>(W_proj, Wpt, CC, CC);

  // QKV GEMM
  gemm_mfma<<<dim3(3 * CC / 128, BB * TT / 128), 256, 0, stream>>>(
      xb, Wat, b_attn, 3 * CC, 0, Q, K, V, nullptr);
  // V -> V^T
  vtrans<<<dim3(TT / 64, BB * HH), 256, 0, stream>>>(V, VtT);
  // attention
  attn_mfma<<<dim3(TT / 64, HH, BB), 256, 0, stream>>>(Q, K, VtT, Yb);
  // proj GEMM
  gemm_mfma<<<dim3(CC / 128, BB * TT / 128), 256, 0, stream>>>(
      Yb, Wpt, b_proj, CC, 1, nullptr, nullptr, nullptr, out);
}

// Round 5
// 139.290 us; speedup vs baseline: 20.5115x; 1.1532x over previous
//
#include <hip/hip_runtime.h>
#include <hip/hip_bf16.h>
#include <math.h>

#define BB 2
#define TT 2048
#define CC 768
#define HH 12
#define DD 64
#define KD 768     // GEMM K dim (both GEMMs)
#define NCH 80     // causal key-chunks per (b,h): sum_q ceil((q+1)/8), q<32

typedef __attribute__((ext_vector_type(8))) short bf16x8;
typedef __attribute__((ext_vector_type(4))) float f32x4;
typedef __attribute__((ext_vector_type(4))) float f32x4v;
typedef __attribute__((ext_vector_type(4))) ushort u16x4;

static __device__ __forceinline__ ushort f2bf(float f) {
  union { float f; unsigned u; } v; v.f = f;
  unsigned r = v.u + 0x7FFF + ((v.u >> 16) & 1);  // RNE
  return (ushort)(r >> 16);
}
static __device__ __forceinline__ float bf2f(ushort u) {
  union { unsigned u; float f; } v; v.u = ((unsigned)u) << 16;
  return v.f;
}

// ---------------------------------------------------------------------------
// fp32 -> bf16 elementwise (n4 = n/4 float4 chunks)
// ---------------------------------------------------------------------------
__global__ __launch_bounds__(256) void cvt_bf16(const float* __restrict__ in,
                                                ushort* __restrict__ out, int n4) {
  int i = blockIdx.x * 256 + threadIdx.x;
  if (i >= n4) return;
  f32x4v v = ((const f32x4v*)in)[i];
  u16x4 o;
  o.x = f2bf(v.x); o.y = f2bf(v.y); o.z = f2bf(v.z); o.w = f2bf(v.w);
  ((u16x4*)out)[i] = o;
}

// ---------------------------------------------------------------------------
// W [K][N] fp32 -> Wt [N][K] bf16 (tiled transpose, both sides coalesced)
// ---------------------------------------------------------------------------
__global__ __launch_bounds__(256) void transpose_cvt(const float* __restrict__ W,
                                                     ushort* __restrict__ Wt,
                                                     int K, int N) {
  __shared__ float t[32][33];
  const int n0 = blockIdx.x * 32, k0 = blockIdx.y * 32;
  const int tx = threadIdx.x & 31, ty = threadIdx.x >> 5;  // 32 x 8
#pragma unroll
  for (int j = 0; j < 32; j += 8)
    t[ty + j][tx] = W[(size_t)(k0 + ty + j) * N + n0 + tx];
  __syncthreads();
#pragma unroll
  for (int j = 0; j < 32; j += 8)
    Wt[(size_t)(n0 + ty + j) * K + k0 + tx] = f2bf(t[tx][ty + j]);
}

// ---------------------------------------------------------------------------
// V [bh][T][D] bf16 -> Vt [bh][D][T] bf16 (64x64 tiles via LDS)
// ---------------------------------------------------------------------------
__global__ __launch_bounds__(256) void vtrans(const ushort* __restrict__ V,
                                              ushort* __restrict__ Vt) {
  __shared__ ushort t[64][72];
  const int t0 = blockIdx.x * 64;
  const size_t base = (size_t)blockIdx.y * TT * DD;
  const int tid = threadIdx.x;
  const int r = tid >> 2, c = (tid & 3) * 16;
  *(bf16x8*)&t[r][c] = *(const bf16x8*)&V[base + (size_t)(t0 + r) * DD + c];
  *(bf16x8*)&t[r][c + 8] = *(const bf16x8*)&V[base + (size_t)(t0 + r) * DD + c + 8];
  __syncthreads();
  const int d = tid >> 2, tc = (tid & 3) * 16;
  bf16x8 o0, o1;
#pragma unroll
  for (int j = 0; j < 8; ++j) { o0[j] = (short)t[tc + j][d]; o1[j] = (short)t[tc + 8 + j][d]; }
  *(bf16x8*)&Vt[base + (size_t)d * TT + t0 + tc] = o0;
  *(bf16x8*)&Vt[base + (size_t)d * TT + t0 + tc + 8] = o1;
}

// ---------------------------------------------------------------------------
// bf16 MFMA GEMM (m97 structure) — unchanged (verified).
// ---------------------------------------------------------------------------
__global__ __launch_bounds__(256) void gemm_mfma(
    const ushort* __restrict__ A, const ushort* __restrict__ Bt,
    const float* __restrict__ bias, int N, int mode,
    ushort* __restrict__ Qo, ushort* __restrict__ Ko, ushort* __restrict__ Vo,
    float* __restrict__ Of) {
  __shared__ ushort As[128 * 32];
  __shared__ ushort Bs[128 * 32];
  const int tid = threadIdx.x;
  const int w = tid >> 6, lane = tid & 63;
  const int wr = w >> 1, wc = w & 1;
  const int grp = lane >> 4, colk = lane & 15;
  const int bm = blockIdx.y * 128, bn = blockIdx.x * 128;

  f32x4 acc[4][4] = {};

  auto* AsL = (__attribute__((address_space(3))) char*)As;
  auto* BsL = (__attribute__((address_space(3))) char*)Bs;

  for (int k0 = 0; k0 < KD; k0 += 32) {
#pragma unroll
    for (int i = 0; i < 2; ++i) {
      const int idx = tid + i * 256;
      const int row = idx >> 2, g = idx & 3;
      const int eoff = (g * 8) ^ ((row & 3) << 3);
      const ushort* sa = A + (size_t)(bm + row) * KD + k0 + eoff;
      const ushort* sb = Bt + (size_t)(bn + row) * KD + k0 + eoff;
      __builtin_amdgcn_global_load_lds(
          (const __attribute__((address_space(1))) void*)sa,
          (__attribute__((address_space(3))) void*)(AsL + w * 1024 + i * 4096), 16, 0, 0);
      __builtin_amdgcn_global_load_lds(
          (const __attribute__((address_space(1))) void*)sb,
          (__attribute__((address_space(3))) void*)(BsL + w * 1024 + i * 4096), 16, 0, 0);
    }
    __syncthreads();

    bf16x8 af[4], bf[4];
    const int sw = (colk & 3) << 3;
#pragma unroll
    for (int m = 0; m < 4; ++m)
      af[m] = *(const bf16x8*)&As[(wr * 64 + m * 16 + colk) * 32 + ((grp * 8) ^ sw)];
#pragma unroll
    for (int n = 0; n < 4; ++n)
      bf[n] = *(const bf16x8*)&Bs[(wc * 64 + n * 16 + colk) * 32 + ((grp * 8) ^ sw)];
#pragma unroll
    for (int m = 0; m < 4; ++m)
#pragma unroll
      for (int n = 0; n < 4; ++n)
        acc[m][n] = __builtin_amdgcn_mfma_f32_16x16x32_bf16(af[m], bf[n], acc[m][n], 0, 0, 0);
    __syncthreads();
  }

#pragma unroll
  for (int m = 0; m < 4; ++m) {
    const int gro = bm + wr * 64 + m * 16 + grp * 4;
#pragma unroll
    for (int n = 0; n < 4; ++n) {
      const int col = bn + wc * 64 + n * 16 + colk;
      const float bv = bias[col];
#pragma unroll
      for (int j = 0; j < 4; ++j) {
        const int row = gro + j;
        const float v = acc[m][n][j] + bv;
        if (mode == 0) {
          const int which = col / CC;
          const int c = col - which * CC;
          const int hh = c >> 6, d = c & 63;
          const int b = row >> 11, t = row & 2047;
          const size_t di = ((size_t)((b * HH + hh) * TT + t)) * DD + d;
          const ushort bvv = f2bf(v);
          if (which == 0) Qo[di] = bvv;
          else if (which == 1) Ko[di] = bvv;
          else Vo[di] = bvv;
        } else {
          Of[(size_t)row * N + col] = v;
        }
      }
    }
  }
}

// ---------------------------------------------------------------------------
// Flash attention, SPLIT-K over key chunks (<=512 keys / <=8 KV-tiles each).
// One block per (chunk c, h, b); chunk c -> (q-tile qq, chunk-idx ci).
// Writes unnormalized partials: Po (bf16 o), Pml (fp32 m,l) per row.
// Per-tile math identical to round 4 (verified). KVBLK=64, T14 prefetch.
// ---------------------------------------------------------------------------
__global__ __launch_bounds__(256) void attn_mfma(
    const ushort* __restrict__ Q, const ushort* __restrict__ K,
    const ushort* __restrict__ Vt, ushort* __restrict__ Po,
    float* __restrict__ Pml) {
  const int c = NCH - 1 - (int)blockIdx.x;  // heavy chunks first
  int qq, ci;
  if (c < 8)       { qq = c;                              ci = 0; }
  else if (c < 24) { int o_ = c - 8;  qq = 8  + (o_ >> 1); ci = o_ & 1; }
  else if (c < 48) { int o_ = c - 24; qq = 16 + o_ / 3;    ci = o_ % 3; }
  else             { int o_ = c - 48; qq = 24 + (o_ >> 2); ci = o_ & 3; }
  const int h = blockIdx.y, b = blockIdx.z;
  const int bh = b * HH + h;
  const size_t hb = (size_t)bh * TT * DD;
  const int kbase = ci * 512;
  const int nt = min(8, qq + 1 - ci * 8);  // >= 1

  __shared__ ushort Ks[64][72];     // [key][d]
  __shared__ ushort Vs[64][72];     // [d][key]
  __shared__ ushort Ps[4][16][72];  // per-wave P [qrow][key]

  const int tid = threadIdx.x;
  const int w = tid >> 6, lane = tid & 63;
  const int grp = lane >> 4, colk = lane & 15;
  const int q0w = qq * 64 + w * 16;

  const ushort* Kg = K + hb;
  const ushort* Vg = Vt + hb;  // [d][t]

  bf16x8 qf[2];
  {
    const ushort* qp = Q + hb + (size_t)(q0w + colk) * DD + 8 * grp;
    qf[0] = *(const bf16x8*)(qp);
    qf[1] = *(const bf16x8*)(qp + 32);
  }

  f32x4 o[4] = {};
  float m[4], l[4];
#pragma unroll
  for (int r = 0; r < 4; ++r) { m[r] = -1e30f; l[r] = 0.f; }

  const int srow = tid >> 2;          // 0..63
  const int scol = (tid & 3) * 16;    // 0,16,32,48

  // prologue: stage tile 0 of this chunk
  {
    bf16x8 k0a = *(const bf16x8*)&Kg[(size_t)(kbase + srow) * DD + scol];
    bf16x8 k0b = *(const bf16x8*)&Kg[(size_t)(kbase + srow) * DD + scol + 8];
    bf16x8 v0a = *(const bf16x8*)&Vg[(size_t)srow * TT + kbase + scol];
    bf16x8 v0b = *(const bf16x8*)&Vg[(size_t)srow * TT + kbase + scol + 8];
    *(bf16x8*)&Ks[srow][scol] = k0a;
    *(bf16x8*)&Ks[srow][scol + 8] = k0b;
    *(bf16x8*)&Vs[srow][scol] = v0a;
    *(bf16x8*)&Vs[srow][scol + 8] = v0b;
  }
  __syncthreads();

  for (int it = 0; it < nt; ++it) {
    const int k0 = kbase + it * 64;
    const bool pfn = (it + 1 < nt);
    bf16x8 nk0, nk1, nv0, nv1;
    if (pfn) {  // issue next-tile loads early; latency hides under compute
      nk0 = *(const bf16x8*)&Kg[(size_t)(k0 + 64 + srow) * DD + scol];
      nk1 = *(const bf16x8*)&Kg[(size_t)(k0 + 64 + srow) * DD + scol + 8];
      nv0 = *(const bf16x8*)&Vg[(size_t)srow * TT + k0 + 64 + scol];
      nv1 = *(const bf16x8*)&Vg[(size_t)srow * TT + k0 + 64 + scol + 8];
    }

    if (k0 <= q0w + 15) {  // wave-uniform causal guard
      // ---- QK^T: 16q x 64k ----
      f32x4 s[4] = {};
#pragma unroll
      for (int dh = 0; dh < 2; ++dh) {
#pragma unroll
        for (int kb = 0; kb < 4; ++kb) {
          bf16x8 kf = *(const bf16x8*)&Ks[16 * kb + colk][8 * grp + 32 * dh];
          s[kb] = __builtin_amdgcn_mfma_f32_16x16x32_bf16(qf[dh], kf, s[kb], 0, 0, 0);
        }
      }

      // ---- online softmax (per q-row r) ----
#pragma unroll
      for (int r = 0; r < 4; ++r) {
        const int qg = q0w + grp * 4 + r;
        float a[4];
#pragma unroll
        for (int kb = 0; kb < 4; ++kb) {
          a[kb] = s[kb][r] * 0.125f;
          if (k0 + 16 * kb + colk > qg) a[kb] = -1e30f;
        }
        float pm = fmaxf(fmaxf(a[0], a[1]), fmaxf(a[2], a[3]));
#pragma unroll
        for (int off = 8; off; off >>= 1) pm = fmaxf(pm, __shfl_xor(pm, off));
        const float mn = fmaxf(m[r], pm);
        const float sc = __expf(m[r] - mn);
        m[r] = mn;
        float p[4], ps = 0.f;
#pragma unroll
        for (int kb = 0; kb < 4; ++kb) { p[kb] = __expf(a[kb] - mn); ps += p[kb]; }
#pragma unroll
        for (int off = 8; off; off >>= 1) ps += __shfl_xor(ps, off);
        l[r] = l[r] * sc + ps;
#pragma unroll
        for (int n = 0; n < 4; ++n) o[n][r] *= sc;
#pragma unroll
        for (int kb = 0; kb < 4; ++kb) Ps[w][grp * 4 + r][16 * kb + colk] = f2bf(p[kb]);
      }

      // ---- PV (same-wave LDS round trip, lgkmcnt-ordered) ----
      bf16x8 pf0 = *(const bf16x8*)&Ps[w][colk][8 * grp];
      bf16x8 pf1 = *(const bf16x8*)&Ps[w][colk][32 + 8 * grp];
#pragma unroll
      for (int n = 0; n < 4; ++n) {
        bf16x8 vf0 = *(const bf16x8*)&Vs[16 * n + colk][8 * grp];
        bf16x8 vf1 = *(const bf16x8*)&Vs[16 * n + colk][32 + 8 * grp];
        o[n] = __builtin_amdgcn_mfma_f32_16x16x32_bf16(pf0, vf0, o[n], 0, 0, 0);
        o[n] = __builtin_amdgcn_mfma_f32_16x16x32_bf16(pf1, vf1, o[n], 0, 0, 0);
      }
    }

    if (pfn) {
      __syncthreads();
      *(bf16x8*)&Ks[srow][scol] = nk0;
      *(bf16x8*)&Ks[srow][scol + 8] = nk1;
      *(bf16x8*)&Vs[srow][scol] = nv0;
      *(bf16x8*)&Vs[srow][scol + 8] = nv1;
      __syncthreads();
    }
  }

  // epilogue: unnormalized partials
  const size_t pbase = ((size_t)bh * NCH + c) * 64;
#pragma unroll
  for (int r = 0; r < 4; ++r) {
    const int row = w * 16 + grp * 4 + r;
#pragma unroll
    for (int n = 0; n < 4; ++n)
      Po[(pbase + row) * 64 + 16 * n + colk] = f2bf(o[n][r]);
    if (colk == 0) {
      Pml[(pbase + row) * 2] = m[r];
      Pml[(pbase + row) * 2 + 1] = l[r];
    }
  }
}

// ---------------------------------------------------------------------------
// Merge partials: Y[row] = sum_i exp(m_i-M) * o_i[row] / sum_i exp(m_i-M)*l_i
// One block per (q-tile, h, b); thread owns (row, 16-d slab).
// ---------------------------------------------------------------------------
__global__ __launch_bounds__(256) void attn_merge(
    const ushort* __restrict__ Po, const float* __restrict__ Pml,
    ushort* __restrict__ Yb) {
  const int qq = blockIdx.x, h = blockIdx.y, b = blockIdx.z;
  const int bh = b * HH + h;
  const int g = qq >> 3;
  const int nch = g + 1;
  const int gb = (g == 0) ? 0 : (g == 1) ? 8 : (g == 2) ? 24 : 48;
  const int cb = gb + nch * (qq - 8 * g);

  const int tid = threadIdx.x;
  const int row = tid >> 2;
  const int d0 = (tid & 3) * 16;

  float mi[4], li[4];
  float M = -1e30f;
#pragma unroll
  for (int i = 0; i < 4; ++i) {
    if (i < nch) {
      const size_t pb = ((size_t)bh * NCH + cb + i) * 64 + row;
      mi[i] = Pml[pb * 2];
      li[i] = Pml[pb * 2 + 1];
      M = fmaxf(M, mi[i]);
    }
  }
  float acc[16] = {};
  float lt = 0.f;
#pragma unroll
  for (int i = 0; i < 4; ++i) {
    if (i < nch) {
      const float wgt = __expf(mi[i] - M);
      lt += li[i] * wgt;
      const ushort* pp = Po + (((size_t)bh * NCH + cb + i) * 64 + row) * 64 + d0;
      bf16x8 a = *(const bf16x8*)pp;
      bf16x8 bv = *(const bf16x8*)(pp + 8);
#pragma unroll
      for (int j = 0; j < 8; ++j) {
        acc[j] += wgt * bf2f((ushort)a[j]);
        acc[8 + j] += wgt * bf2f((ushort)bv[j]);
      }
    }
  }
  const float inv = 1.0f / lt;
  const int t = qq * 64 + row;
  ushort* yp = Yb + ((size_t)(b * TT) + t) * CC + h * DD + d0;
  bf16x8 o0, o1;
#pragma unroll
  for (int j = 0; j < 8; ++j) {
    o0[j] = (short)f2bf(acc[j] * inv);
    o1[j] = (short)f2bf(acc[8 + j] * inv);
  }
  *(bf16x8*)yp = o0;
  *(bf16x8*)(yp + 8) = o1;
}

extern "C" void kernel_launch(void* const* d_in, const int* in_sizes, int n_in,
                              void* d_out, int out_size, void* d_ws, size_t ws_size,
                              hipStream_t stream) {
  const float* x      = (const float*)d_in[0];
  const float* W_attn = (const float*)d_in[1];
  const float* b_attn = (const float*)d_in[2];
  const float* W_proj = (const float*)d_in[3];
  const float* b_proj = (const float*)d_in[4];
  float* out = (float*)d_out;

  const size_t per = (size_t)BB * TT * CC;  // 3,145,728
  ushort* Q   = (ushort*)d_ws;
  ushort* K   = Q + per;
  ushort* V   = K + per;
  ushort* Yb  = V + per;
  ushort* VtT = Yb + per;                   // [bh][D][T]
  ushort* Wpt = VtT + per;                  // [768][768]
  // union region: {xb, Wat} dead after QKV GEMM; Po/Pml alias it.
  ushort* xb  = Wpt + (size_t)CC * CC;
  ushort* Wat = xb + per;                   // [2304][768]
  ushort* Po  = xb;                         // [bh][NCH][64][64] bf16
  float*  Pml = (float*)(Po + (size_t)BB * HH * NCH * 64 * 64);  // [..][64][2] f32
  // total ws use: ~49.4 MB

  // prep
  cvt_bf16<<<dim3((per / 4 + 255) / 256), 256, 0, stream>>>(x, xb, (int)(per / 4));
  transpose_cvt<<<dim3(3 * CC / 32, CC / 32), 256, 0, stream>>>(W_attn, Wat, CC, 3 * CC);
  transpose_cvt<<<dim3(CC / 32, CC / 32), 256, 0, stream>>>(W_proj, Wpt, CC, CC);

  // QKV GEMM
  gemm_mfma<<<dim3(3 * CC / 128, BB * TT / 128), 256, 0, stream>>>(
      xb, Wat, b_attn, 3 * CC, 0, Q, K, V, nullptr);
  // V -> V^T
  vtrans<<<dim3(TT / 64, BB * HH), 256, 0, stream>>>(V, VtT);
  // attention split-K: one block per (chunk, h, b)
  attn_mfma<<<dim3(NCH, HH, BB), 256, 0, stream>>>(Q, K, VtT, Po, Pml);
  // merge partials -> Yb
  attn_merge<<<dim3(TT / 64, HH, BB), 256, 0, stream>>>(Po, Pml, Yb);
  // proj GEMM
  gemm_mfma<<<dim3(CC / 128, BB * TT / 128), 256, 0, stream>>>(
      Yb, Wpt, b_proj, CC, 1, nullptr, nullptr, nullptr, out);
}

// Round 6
// 136.916 us; speedup vs baseline: 20.8671x; 1.0173x over previous
//
#include <hip/hip_runtime.h>
#include <hip/hip_bf16.h>
#include <math.h>

#define BB 2
#define TT 2048
#define CC 768
#define HH 12
#define DD 64
#define KD 768     // GEMM K dim (both GEMMs)
#define NCH 80     // causal key-chunks per (b,h): sum_q ceil((q+1)/8), q<32

// Q is pre-scaled by 1/sqrt(64) * log2(e) so softmax runs in base-2 domain.
#define QSCALE 0.18033688011112044f
#define THR2 11.5f  // defer-max threshold (base-2 units, ~e^8)

typedef __attribute__((ext_vector_type(8))) short bf16x8;
typedef __attribute__((ext_vector_type(4))) float f32x4;
typedef __attribute__((ext_vector_type(4))) float f32x4v;
typedef __attribute__((ext_vector_type(4))) ushort u16x4;

static __device__ __forceinline__ ushort f2bf(float f) {
  union { float f; unsigned u; } v; v.f = f;
  unsigned r = v.u + 0x7FFF + ((v.u >> 16) & 1);  // RNE
  return (ushort)(r >> 16);
}
static __device__ __forceinline__ float bf2f(ushort u) {
  union { unsigned u; float f; } v; v.u = ((unsigned)u) << 16;
  return v.f;
}

// ---------------------------------------------------------------------------
// fp32 -> bf16 elementwise (n4 = n/4 float4 chunks)
// ---------------------------------------------------------------------------
__global__ __launch_bounds__(256) void cvt_bf16(const float* __restrict__ in,
                                                ushort* __restrict__ out, int n4) {
  int i = blockIdx.x * 256 + threadIdx.x;
  if (i >= n4) return;
  f32x4v v = ((const f32x4v*)in)[i];
  u16x4 o;
  o.x = f2bf(v.x); o.y = f2bf(v.y); o.z = f2bf(v.z); o.w = f2bf(v.w);
  ((u16x4*)out)[i] = o;
}

// ---------------------------------------------------------------------------
// W [K][N] fp32 -> Wt [N][K] bf16 (tiled transpose, both sides coalesced)
// ---------------------------------------------------------------------------
__global__ __launch_bounds__(256) void transpose_cvt(const float* __restrict__ W,
                                                     ushort* __restrict__ Wt,
                                                     int K, int N) {
  __shared__ float t[32][33];
  const int n0 = blockIdx.x * 32, k0 = blockIdx.y * 32;
  const int tx = threadIdx.x & 31, ty = threadIdx.x >> 5;  // 32 x 8
#pragma unroll
  for (int j = 0; j < 32; j += 8)
    t[ty + j][tx] = W[(size_t)(k0 + ty + j) * N + n0 + tx];
  __syncthreads();
#pragma unroll
  for (int j = 0; j < 32; j += 8)
    Wt[(size_t)(n0 + ty + j) * K + k0 + tx] = f2bf(t[tx][ty + j]);
}

// ---------------------------------------------------------------------------
// V [bh][T][D] bf16 -> Vt [bh][D][T] bf16 (64x64 tiles via LDS)
// ---------------------------------------------------------------------------
__global__ __launch_bounds__(256) void vtrans(const ushort* __restrict__ V,
                                              ushort* __restrict__ Vt) {
  __shared__ ushort t[64][72];
  const int t0 = blockIdx.x * 64;
  const size_t base = (size_t)blockIdx.y * TT * DD;
  const int tid = threadIdx.x;
  const int r = tid >> 2, c = (tid & 3) * 16;
  *(bf16x8*)&t[r][c] = *(const bf16x8*)&V[base + (size_t)(t0 + r) * DD + c];
  *(bf16x8*)&t[r][c + 8] = *(const bf16x8*)&V[base + (size_t)(t0 + r) * DD + c + 8];
  __syncthreads();
  const int d = tid >> 2, tc = (tid & 3) * 16;
  bf16x8 o0, o1;
#pragma unroll
  for (int j = 0; j < 8; ++j) { o0[j] = (short)t[tc + j][d]; o1[j] = (short)t[tc + 8 + j][d]; }
  *(bf16x8*)&Vt[base + (size_t)d * TT + t0 + tc] = o0;
  *(bf16x8*)&Vt[base + (size_t)d * TT + t0 + tc + 8] = o1;
}

// ---------------------------------------------------------------------------
// bf16 MFMA GEMM (m97 structure). mode 0 additionally pre-scales Q by QSCALE.
// ---------------------------------------------------------------------------
__global__ __launch_bounds__(256) void gemm_mfma(
    const ushort* __restrict__ A, const ushort* __restrict__ Bt,
    const float* __restrict__ bias, int N, int mode,
    ushort* __restrict__ Qo, ushort* __restrict__ Ko, ushort* __restrict__ Vo,
    float* __restrict__ Of) {
  __shared__ ushort As[128 * 32];
  __shared__ ushort Bs[128 * 32];
  const int tid = threadIdx.x;
  const int w = tid >> 6, lane = tid & 63;
  const int wr = w >> 1, wc = w & 1;
  const int grp = lane >> 4, colk = lane & 15;
  const int bm = blockIdx.y * 128, bn = blockIdx.x * 128;

  f32x4 acc[4][4] = {};

  auto* AsL = (__attribute__((address_space(3))) char*)As;
  auto* BsL = (__attribute__((address_space(3))) char*)Bs;

  for (int k0 = 0; k0 < KD; k0 += 32) {
#pragma unroll
    for (int i = 0; i < 2; ++i) {
      const int idx = tid + i * 256;
      const int row = idx >> 2, g = idx & 3;
      const int eoff = (g * 8) ^ ((row & 3) << 3);
      const ushort* sa = A + (size_t)(bm + row) * KD + k0 + eoff;
      const ushort* sb = Bt + (size_t)(bn + row) * KD + k0 + eoff;
      __builtin_amdgcn_global_load_lds(
          (const __attribute__((address_space(1))) void*)sa,
          (__attribute__((address_space(3))) void*)(AsL + w * 1024 + i * 4096), 16, 0, 0);
      __builtin_amdgcn_global_load_lds(
          (const __attribute__((address_space(1))) void*)sb,
          (__attribute__((address_space(3))) void*)(BsL + w * 1024 + i * 4096), 16, 0, 0);
    }
    __syncthreads();

    bf16x8 af[4], bf[4];
    const int sw = (colk & 3) << 3;
#pragma unroll
    for (int m = 0; m < 4; ++m)
      af[m] = *(const bf16x8*)&As[(wr * 64 + m * 16 + colk) * 32 + ((grp * 8) ^ sw)];
#pragma unroll
    for (int n = 0; n < 4; ++n)
      bf[n] = *(const bf16x8*)&Bs[(wc * 64 + n * 16 + colk) * 32 + ((grp * 8) ^ sw)];
#pragma unroll
    for (int m = 0; m < 4; ++m)
#pragma unroll
      for (int n = 0; n < 4; ++n)
        acc[m][n] = __builtin_amdgcn_mfma_f32_16x16x32_bf16(af[m], bf[n], acc[m][n], 0, 0, 0);
    __syncthreads();
  }

#pragma unroll
  for (int m = 0; m < 4; ++m) {
    const int gro = bm + wr * 64 + m * 16 + grp * 4;
#pragma unroll
    for (int n = 0; n < 4; ++n) {
      const int col = bn + wc * 64 + n * 16 + colk;
      const float bv = bias[col];
#pragma unroll
      for (int j = 0; j < 4; ++j) {
        const int row = gro + j;
        float v = acc[m][n][j] + bv;
        if (mode == 0) {
          const int which = col / CC;
          const int c = col - which * CC;
          const int hh = c >> 6, d = c & 63;
          const int b = row >> 11, t = row & 2047;
          const size_t di = ((size_t)((b * HH + hh) * TT + t)) * DD + d;
          if (which == 0) v *= QSCALE;  // fold softmax scale + log2e into Q
          const ushort bvv = f2bf(v);
          if (which == 0) Qo[di] = bvv;
          else if (which == 1) Ko[di] = bvv;
          else Vo[di] = bvv;
        } else {
          Of[(size_t)row * N + col] = v;
        }
      }
    }
  }
}

// ---------------------------------------------------------------------------
// Flash attention split-K, bf16 MFMA. Base-2 softmax (Q pre-scaled), masks
// only on diagonal tiles, defer-max (THR2), row-sum via ones-MFMA.
// ---------------------------------------------------------------------------
__global__ __launch_bounds__(256) void attn_mfma(
    const ushort* __restrict__ Q, const ushort* __restrict__ K,
    const ushort* __restrict__ Vt, ushort* __restrict__ Po,
    float* __restrict__ Pml) {
  const int c = NCH - 1 - (int)blockIdx.x;  // heavy chunks first
  int qq, ci;
  if (c < 8)       { qq = c;                              ci = 0; }
  else if (c < 24) { int o_ = c - 8;  qq = 8  + (o_ >> 1); ci = o_ & 1; }
  else if (c < 48) { int o_ = c - 24; qq = 16 + o_ / 3;    ci = o_ % 3; }
  else             { int o_ = c - 48; qq = 24 + (o_ >> 2); ci = o_ & 3; }
  const int h = blockIdx.y, b = blockIdx.z;
  const int bh = b * HH + h;
  const size_t hb = (size_t)bh * TT * DD;
  const int kbase = ci * 512;
  const int nt = min(8, qq + 1 - ci * 8);  // >= 1

  __shared__ ushort Ks[64][72];     // [key][d]
  __shared__ ushort Vs[64][72];     // [d][key]
  __shared__ ushort Ps[4][16][72];  // per-wave P [qrow][key]

  const int tid = threadIdx.x;
  const int w = tid >> 6, lane = tid & 63;
  const int grp = lane >> 4, colk = lane & 15;
  const int q0w = qq * 64 + w * 16;

  const ushort* Kg = K + hb;
  const ushort* Vg = Vt + hb;  // [d][t]

  bf16x8 qf[2];
  {
    const ushort* qp = Q + hb + (size_t)(q0w + colk) * DD + 8 * grp;
    qf[0] = *(const bf16x8*)(qp);
    qf[1] = *(const bf16x8*)(qp + 32);
  }
  bf16x8 onesf;
#pragma unroll
  for (int j = 0; j < 8; ++j) onesf[j] = (short)0x3F80;  // bf16 1.0

  f32x4 o[4] = {};
  float m[4], l[4];
#pragma unroll
  for (int r = 0; r < 4; ++r) { m[r] = -1e30f; l[r] = 0.f; }

  const int srow = tid >> 2;          // 0..63
  const int scol = (tid & 3) * 16;    // 0,16,32,48

  // prologue: stage tile 0 of this chunk
  {
    bf16x8 k0a = *(const bf16x8*)&Kg[(size_t)(kbase + srow) * DD + scol];
    bf16x8 k0b = *(const bf16x8*)&Kg[(size_t)(kbase + srow) * DD + scol + 8];
    bf16x8 v0a = *(const bf16x8*)&Vg[(size_t)srow * TT + kbase + scol];
    bf16x8 v0b = *(const bf16x8*)&Vg[(size_t)srow * TT + kbase + scol + 8];
    *(bf16x8*)&Ks[srow][scol] = k0a;
    *(bf16x8*)&Ks[srow][scol + 8] = k0b;
    *(bf16x8*)&Vs[srow][scol] = v0a;
    *(bf16x8*)&Vs[srow][scol + 8] = v0b;
  }
  __syncthreads();

  for (int it = 0; it < nt; ++it) {
    const int k0 = kbase + it * 64;
    const bool pfn = (it + 1 < nt);
    bf16x8 nk0, nk1, nv0, nv1;
    if (pfn) {  // issue next-tile loads early; latency hides under compute
      nk0 = *(const bf16x8*)&Kg[(size_t)(k0 + 64 + srow) * DD + scol];
      nk1 = *(const bf16x8*)&Kg[(size_t)(k0 + 64 + srow) * DD + scol + 8];
      nv0 = *(const bf16x8*)&Vg[(size_t)srow * TT + k0 + 64 + scol];
      nv1 = *(const bf16x8*)&Vg[(size_t)srow * TT + k0 + 64 + scol + 8];
    }

    if (k0 <= q0w) {  // wave-uniform causal guard (16-alignment => every row valid)
      // ---- QK^T: 16q x 64k (scores already in base-2 units via QSCALE) ----
      f32x4 s[4] = {};
#pragma unroll
      for (int dh = 0; dh < 2; ++dh) {
#pragma unroll
        for (int kb = 0; kb < 4; ++kb) {
          bf16x8 kf = *(const bf16x8*)&Ks[16 * kb + colk][8 * grp + 32 * dh];
          s[kb] = __builtin_amdgcn_mfma_f32_16x16x32_bf16(qf[dh], kf, s[kb], 0, 0, 0);
        }
      }

      const bool diag = (k0 + 63 > q0w);  // wave-uniform: masking needed?
      float a[4][4], pmv[4];
#pragma unroll
      for (int r = 0; r < 4; ++r) {
        const int qg = q0w + grp * 4 + r;
#pragma unroll
        for (int kb = 0; kb < 4; ++kb) {
          float v = s[kb][r];
          if (diag && (k0 + 16 * kb + colk > qg)) v = -1e30f;
          a[r][kb] = v;
        }
        float pm = fmaxf(fmaxf(a[r][0], a[r][1]), fmaxf(a[r][2], a[r][3]));
#pragma unroll
        for (int off = 8; off; off >>= 1) pm = fmaxf(pm, __shfl_xor(pm, off));
        pmv[r] = pm;
      }

      // defer-max: rescale only when some row's max grew past THR2
      const bool need = (pmv[0] > m[0] + THR2) || (pmv[1] > m[1] + THR2) ||
                        (pmv[2] > m[2] + THR2) || (pmv[3] > m[3] + THR2);
      if (__any(need)) {
#pragma unroll
        for (int r = 0; r < 4; ++r) {
          const float mn = fmaxf(m[r], pmv[r]);
          const float sc = exp2f(m[r] - mn);
          m[r] = mn;
          l[r] *= sc;
#pragma unroll
          for (int n = 0; n < 4; ++n) o[n][r] *= sc;
        }
      }

      // P = 2^(a - m), staged to LDS for the PV A-fragment
#pragma unroll
      for (int r = 0; r < 4; ++r)
#pragma unroll
        for (int kb = 0; kb < 4; ++kb)
          Ps[w][grp * 4 + r][16 * kb + colk] = f2bf(exp2f(a[r][kb] - m[r]));

      bf16x8 pf0 = *(const bf16x8*)&Ps[w][colk][8 * grp];
      bf16x8 pf1 = *(const bf16x8*)&Ps[w][colk][32 + 8 * grp];

      // row-sum of P via ones-MFMA (replaces shfl-add chains)
      f32x4 ls = {};
      ls = __builtin_amdgcn_mfma_f32_16x16x32_bf16(pf0, onesf, ls, 0, 0, 0);
      ls = __builtin_amdgcn_mfma_f32_16x16x32_bf16(pf1, onesf, ls, 0, 0, 0);
#pragma unroll
      for (int r = 0; r < 4; ++r) l[r] += ls[r];

      // ---- PV ----
#pragma unroll
      for (int n = 0; n < 4; ++n) {
        bf16x8 vf0 = *(const bf16x8*)&Vs[16 * n + colk][8 * grp];
        bf16x8 vf1 = *(const bf16x8*)&Vs[16 * n + colk][32 + 8 * grp];
        o[n] = __builtin_amdgcn_mfma_f32_16x16x32_bf16(pf0, vf0, o[n], 0, 0, 0);
        o[n] = __builtin_amdgcn_mfma_f32_16x16x32_bf16(pf1, vf1, o[n], 0, 0, 0);
      }
    }

    if (pfn) {
      __syncthreads();
      *(bf16x8*)&Ks[srow][scol] = nk0;
      *(bf16x8*)&Ks[srow][scol + 8] = nk1;
      *(bf16x8*)&Vs[srow][scol] = nv0;
      *(bf16x8*)&Vs[srow][scol + 8] = nv1;
      __syncthreads();
    }
  }

  // epilogue: unnormalized partials (m in base-2 domain)
  const size_t pbase = ((size_t)bh * NCH + c) * 64;
#pragma unroll
  for (int r = 0; r < 4; ++r) {
    const int row = w * 16 + grp * 4 + r;
#pragma unroll
    for (int n = 0; n < 4; ++n)
      Po[(pbase + row) * 64 + 16 * n + colk] = f2bf(o[n][r]);
    if (colk == 0) {
      Pml[(pbase + row) * 2] = m[r];
      Pml[(pbase + row) * 2 + 1] = l[r];
    }
  }
}

// ---------------------------------------------------------------------------
// Merge partials (base-2 weights): Y = sum_i 2^(m_i-M) o_i / sum_i 2^(m_i-M) l_i
// ---------------------------------------------------------------------------
__global__ __launch_bounds__(256) void attn_merge(
    const ushort* __restrict__ Po, const float* __restrict__ Pml,
    ushort* __restrict__ Yb) {
  const int qq = blockIdx.x, h = blockIdx.y, b = blockIdx.z;
  const int bh = b * HH + h;
  const int g = qq >> 3;
  const int nch = g + 1;
  const int gb = (g == 0) ? 0 : (g == 1) ? 8 : (g == 2) ? 24 : 48;
  const int cb = gb + nch * (qq - 8 * g);

  const int tid = threadIdx.x;
  const int row = tid >> 2;
  const int d0 = (tid & 3) * 16;

  float mi[4], li[4];
  float M = -1e30f;
#pragma unroll
  for (int i = 0; i < 4; ++i) {
    if (i < nch) {
      const size_t pb = ((size_t)bh * NCH + cb + i) * 64 + row;
      mi[i] = Pml[pb * 2];
      li[i] = Pml[pb * 2 + 1];
      M = fmaxf(M, mi[i]);
    }
  }
  float acc[16] = {};
  float lt = 0.f;
#pragma unroll
  for (int i = 0; i < 4; ++i) {
    if (i < nch) {
      const float wgt = exp2f(mi[i] - M);
      lt += li[i] * wgt;
      const ushort* pp = Po + (((size_t)bh * NCH + cb + i) * 64 + row) * 64 + d0;
      bf16x8 a = *(const bf16x8*)pp;
      bf16x8 bv = *(const bf16x8*)(pp + 8);
#pragma unroll
      for (int j = 0; j < 8; ++j) {
        acc[j] += wgt * bf2f((ushort)a[j]);
        acc[8 + j] += wgt * bf2f((ushort)bv[j]);
      }
    }
  }
  const float inv = 1.0f / lt;
  const int t = qq * 64 + row;
  ushort* yp = Yb + ((size_t)(b * TT) + t) * CC + h * DD + d0;
  bf16x8 o0, o1;
#pragma unroll
  for (int j = 0; j < 8; ++j) {
    o0[j] = (short)f2bf(acc[j] * inv);
    o1[j] = (short)f2bf(acc[8 + j] * inv);
  }
  *(bf16x8*)yp = o0;
  *(bf16x8*)(yp + 8) = o1;
}

extern "C" void kernel_launch(void* const* d_in, const int* in_sizes, int n_in,
                              void* d_out, int out_size, void* d_ws, size_t ws_size,
                              hipStream_t stream) {
  const float* x      = (const float*)d_in[0];
  const float* W_attn = (const float*)d_in[1];
  const float* b_attn = (const float*)d_in[2];
  const float* W_proj = (const float*)d_in[3];
  const float* b_proj = (const float*)d_in[4];
  float* out = (float*)d_out;

  const size_t per = (size_t)BB * TT * CC;  // 3,145,728
  ushort* Q   = (ushort*)d_ws;
  ushort* K   = Q + per;
  ushort* V   = K + per;
  ushort* Yb  = V + per;
  ushort* VtT = Yb + per;                   // [bh][D][T]
  ushort* Wpt = VtT + per;                  // [768][768]
  // union region: {xb, Wat} dead after QKV GEMM; Po/Pml alias it.
  ushort* xb  = Wpt + (size_t)CC * CC;
  ushort* Wat = xb + per;                   // [2304][768]
  ushort* Po  = xb;                         // [bh][NCH][64][64] bf16
  float*  Pml = (float*)(Po + (size_t)BB * HH * NCH * 64 * 64);  // [..][64][2] f32

  // prep
  cvt_bf16<<<dim3((per / 4 + 255) / 256), 256, 0, stream>>>(x, xb, (int)(per / 4));
  transpose_cvt<<<dim3(3 * CC / 32, CC / 32), 256, 0, stream>>>(W_attn, Wat, CC, 3 * CC);
  transpose_cvt<<<dim3(CC / 32, CC / 32), 256, 0, stream>>>(W_proj, Wpt, CC, CC);

  // QKV GEMM (Q pre-scaled)
  gemm_mfma<<<dim3(3 * CC / 128, BB * TT / 128), 256, 0, stream>>>(
      xb, Wat, b_attn, 3 * CC, 0, Q, K, V, nullptr);
  // V -> V^T
  vtrans<<<dim3(TT / 64, BB * HH), 256, 0, stream>>>(V, VtT);
  // attention split-K
  attn_mfma<<<dim3(NCH, HH, BB), 256, 0, stream>>>(Q, K, VtT, Po, Pml);
  // merge partials -> Yb
  attn_merge<<<dim3(TT / 64, HH, BB), 256, 0, stream>>>(Po, Pml, Yb);
  // proj GEMM
  gemm_mfma<<<dim3(CC / 128, BB * TT / 128), 256, 0, stream>>>(
      Yb, Wpt, b_proj, CC, 1, nullptr, nullptr, nullptr, out);
}